// Round 6
// baseline (342.497 us; speedup 1.0000x reference)
//
#include <hip/hip_runtime.h>
#include <hip/hip_bf16.h>
#include <stdint.h>

typedef __attribute__((ext_vector_type(8))) __bf16 bf16x8;
typedef __attribute__((ext_vector_type(4))) float f32x4;

constexpr int K_DIM = 4096;
constexpr int N_DIM = 11008;
constexpr int M_DIM = 256;   // B*S
constexpr int TM = 256;      // full M per block
constexpr int TN = 64;       // N cols per block
constexpr int BK = 64;       // K per tile
constexpr int NT = 512;      // 8 waves: 4M x 2N, each wave 64M x 32N
constexpr int KT_ALL = K_DIM / BK;   // 64
constexpr int KSPLIT = 3;    // grid = 172*3 = 516 ~ 2 blocks/CU
constexpr int TILE_ELEMS = TN * BK;  // 4096 bf16 = 8 KB per W tile

__device__ __forceinline__ void gload_lds16(const __bf16* gptr, __bf16* lptr) {
  __builtin_amdgcn_global_load_lds(
      (const __attribute__((address_space(1))) uint32_t*)gptr,
      (__attribute__((address_space(3))) uint32_t*)lptr, 16, 0, 0);
}

__device__ __forceinline__ bf16x8 cvt8f(const float4 u0, const float4 u1) {
  bf16x8 v;
  v[0] = (__bf16)u0.x; v[1] = (__bf16)u0.y; v[2] = (__bf16)u0.z; v[3] = (__bf16)u0.w;
  v[4] = (__bf16)u1.x; v[5] = (__bf16)u1.y; v[6] = (__bf16)u1.z; v[7] = (__bf16)u1.w;
  return v;
}
__device__ __forceinline__ bf16x8 cvt8i(const int4 a, const int4 b) {
  bf16x8 v;
  v[0] = (__bf16)(float)a.x; v[1] = (__bf16)(float)a.y;
  v[2] = (__bf16)(float)a.z; v[3] = (__bf16)(float)a.w;
  v[4] = (__bf16)(float)b.x; v[5] = (__bf16)(float)b.y;
  v[6] = (__bf16)(float)b.z; v[7] = (__bf16)(float)b.w;
  return v;
}

// x fp32 [256][4096] -> xws bf16 row-major (coalesced both sides)
__global__ void cvt_x_kernel(const float* __restrict__ x, __bf16* __restrict__ ws) {
  const int i = (blockIdx.x * 256 + threadIdx.x) * 8;
  const float4 u0 = ((const float4*)(x + i))[0];
  const float4 u1 = ((const float4*)(x + i))[1];
  *(bf16x8*)(ws + i) = cvt8f(u0, u1);
}

// w int32 [11008][4096] -> wt bf16 TILE-MAJOR: wt[n_blk][k_tile] = 8 KB tile
// holding rows (n_blk*64..+63) x cols (k_tile*64..+63), pre-swizzled in the
// GEMM's LDS layout (elem (row,chunk) at row*64 + (chunk^(row&7))*8).
// READ side is perfectly sequential (thread i <-> 32B chunk i; wave = 2 KB
// contiguous -> stream-rate DRAM grain). Write side lands in 128 B pieces
// within a 64 KB window (full L2 lines, no RMW). This converts the GEMM's
// W stream from random-256B-chunks into fully contiguous per-block streams.
__global__ void cvt_w_tile_kernel(const int* __restrict__ w, __bf16* __restrict__ wt) {
  const int i = blockIdx.x * 256 + threadIdx.x;  // 11008*512 = 5,636,096 threads
  const int r   = i >> 9;        // W row 0..11007
  const int c8  = i & 511;       // 8-int32 chunk within row
  const int4* p = (const int4*)(w + (size_t)r * K_DIM + c8 * 8);
  const bf16x8 v = cvt8i(p[0], p[1]);
  const int nb = r >> 6, wrow = r & 63;
  const int kt = c8 >> 3, chunk = c8 & 7;
  const int slot = chunk ^ (wrow & 7);
  *(bf16x8*)(wt + (size_t)(nb * KT_ALL + kt) * TILE_ELEMS + wrow * BK + slot * 8) = v;
}

template<bool A_WS, bool W_WS>
__global__ __launch_bounds__(NT, 4) void int8_linear_kernel(
    const float* __restrict__ x,     // [256,4096] fp32 (fallback)
    const __bf16* __restrict__ xws,  // [256,4096] bf16 (A_WS)
    const int*   __restrict__ w,     // [11008,4096] int32 (fallback)
    const __bf16* __restrict__ wt,   // tile-major bf16 (W_WS)
    const float* __restrict__ scale, // [11008]
    const float* __restrict__ bias,  // [11008]
    float*       __restrict__ out)   // [256,11008] fp32, pre-zeroed, atomics
{
  // Identical structure to round 5 (double-buffer, one barrier per phase) —
  // the ONLY change is W's global layout: per phase each block now reads ONE
  // contiguous, pre-swizzled 8 KB tile (1 gload_lds16/thread), and phases
  // walk consecutive tiles -> each block streams a contiguous ~175 KB region.
  __shared__ __bf16 As[2][TM * BK];        // 2 x 32 KB
  __shared__ __bf16 Wsh[2][TILE_ELEMS];    // 2 x 8 KB  -> 80 KB, 2 blocks/CU

  const int tid  = threadIdx.x;
  const int lane = tid & 63;
  const int wv   = tid >> 6;
  const int quad = lane >> 4;
  const int l16  = lane & 15;
  const int m_base = (wv >> 1) * 64;   // 4 M-groups
  const int wn     = wv & 1;           // 2 N-groups
  const int nb     = blockIdx.x;       // N-block 0..171
  const int n_base = nb * TN;
  const int kc     = blockIdx.y;

  // split-K tile range over 64 tiles: {21,21,22}
  const int t0 = (kc * KT_ALL) / KSPLIT;
  const int t1 = ((kc + 1) * KT_ALL) / KSPLIT;
  const int ntile = t1 - t0;

  f32x4 acc[4][2];
#pragma unroll
  for (int i = 0; i < 4; ++i)
#pragma unroll
    for (int j = 0; j < 2; ++j) acc[i][j] = (f32x4){0.f, 0.f, 0.f, 0.f};

  auto stage = [&](int t, int buf) {
    const int kt = t0 + t;
    // W first (the HBM-class stream): one contiguous 8 KB tile.
    if (W_WS) {
      gload_lds16(wt + (size_t)(nb * KT_ALL + kt) * TILE_ELEMS + tid * 8,
                  Wsh[buf] + tid * 8);
    } else {
      const int row = tid >> 3;
      const int k8l = tid & 7;
      const int4* p = (const int4*)(w + (int64_t)(n_base + row) * K_DIM + kt * BK + k8l * 8);
      const bf16x8 v = cvt8i(p[0], p[1]);
      *(bf16x8*)(Wsh[buf] + row * BK + (k8l ^ (row & 7)) * 8) = v;
    }
    // A: 2048 16B-chunks / 512 thr = 4 each; source-swizzled (rule #21),
    // L2-resident (2 MB).
    if (A_WS) {
#pragma unroll
      for (int j = 0; j < 4; ++j) {
        const int c = j * 512 + tid;
        const int row = c >> 3;
        const int k8 = (c & 7) ^ (row & 7);
        gload_lds16(xws + (int64_t)row * K_DIM + kt * BK + k8 * 8, As[buf] + c * 8);
      }
    } else {
#pragma unroll
      for (int j = 0; j < 4; ++j) {
        const int c = j * 512 + tid;
        const int row = c >> 3;
        const int k8 = c & 7;
        const float* s = x + (int64_t)row * K_DIM + kt * BK + k8 * 8;
        const bf16x8 v = cvt8f(((const float4*)s)[0], ((const float4*)s)[1]);
        *(bf16x8*)(As[buf] + row * BK + (k8 ^ (row & 7)) * 8) = v;
      }
    }
  };
  auto compute = [&](const __bf16* abuf, const __bf16* wbuf) {
#pragma unroll
    for (int ks = 0; ks < 2; ++ks) {
      bf16x8 a[4], b[2];
#pragma unroll
      for (int mi = 0; mi < 4; ++mi) {
        const int m = m_base + mi * 16 + l16;
        const int slot = (ks * 4 + quad) ^ (m & 7);
        a[mi] = *(const bf16x8*)(abuf + m * BK + slot * 8);
      }
#pragma unroll
      for (int ni = 0; ni < 2; ++ni) {
        const int n = wn * 32 + ni * 16 + l16;
        const int slot = (ks * 4 + quad) ^ (n & 7);
        b[ni] = *(const bf16x8*)(wbuf + n * BK + slot * 8);
      }
#pragma unroll
      for (int mi = 0; mi < 4; ++mi)
#pragma unroll
        for (int ni = 0; ni < 2; ++ni)
          acc[mi][ni] = __builtin_amdgcn_mfma_f32_16x16x32_bf16(
              a[mi], b[ni], acc[mi][ni], 0, 0, 0);
    }
  };

  // 2-barrier double-buffered loop: stage(t+1) issues BEFORE compute(t).
  stage(0, 0);
  __syncthreads();
  for (int t = 0; t < ntile; ++t) {
    if (t + 1 < ntile) stage(t + 1, (t + 1) & 1);
    compute(As[t & 1], Wsh[t & 1]);
    __syncthreads();
  }

  // Epilogue: C/D layout col=lane&15, row=quad*4+reg (m89-verified).
  // Scale per-partial (linear); bias added exactly once by the kc==0 block.
#pragma unroll
  for (int ni = 0; ni < 2; ++ni) {
    const int col = n_base + wn * 32 + ni * 16 + l16;
    const float sc = scale[col];
    const float bi = (kc == 0) ? bias[col] : 0.0f;
#pragma unroll
    for (int mi = 0; mi < 4; ++mi) {
      const int row0 = m_base + mi * 16 + quad * 4;
#pragma unroll
      for (int r = 0; r < 4; ++r)
        unsafeAtomicAdd(out + (int64_t)(row0 + r) * N_DIM + col,
                        acc[mi][ni][r] * sc + bi);
    }
  }
}

extern "C" void kernel_launch(void* const* d_in, const int* in_sizes, int n_in,
                              void* d_out, int out_size, void* d_ws, size_t ws_size,
                              hipStream_t stream) {
  const float* x     = (const float*)d_in[0];
  const int*   w     = (const int*)d_in[1];
  const float* scale = (const float*)d_in[2];
  const float* bias  = (const float*)d_in[3];
  float* out = (float*)d_out;

  const size_t xws_bytes = (size_t)M_DIM * K_DIM * sizeof(__bf16);   // 2 MB
  const size_t wt_bytes  = (size_t)N_DIM * K_DIM * sizeof(__bf16);   // 90.2 MB
  __bf16* xws = (__bf16*)d_ws;
  __bf16* wt  = (__bf16*)((char*)d_ws + xws_bytes);

  // split-K partials accumulate via atomics -> zero the output first
  hipMemsetAsync(out, 0, (size_t)M_DIM * N_DIM * sizeof(float), stream);

  dim3 grid(N_DIM / TN, KSPLIT), block(NT);
  if (ws_size >= xws_bytes + wt_bytes) {
    cvt_x_kernel<<<M_DIM * K_DIM / 2048, 256, 0, stream>>>(x, xws);
    cvt_w_tile_kernel<<<(int)(((size_t)N_DIM * K_DIM / 8) / 256), 256, 0, stream>>>(w, wt);
    int8_linear_kernel<true, true><<<grid, block, 0, stream>>>(
        x, xws, w, wt, scale, bias, out);
  } else if (ws_size >= xws_bytes) {
    cvt_x_kernel<<<M_DIM * K_DIM / 2048, 256, 0, stream>>>(x, xws);
    int8_linear_kernel<true, false><<<grid, block, 0, stream>>>(
        x, xws, w, wt, scale, bias, out);
  } else {
    int8_linear_kernel<false, false><<<grid, block, 0, stream>>>(
        x, xws, w, wt, scale, bias, out);
  }
}

// Round 7
// 339.196 us; speedup vs baseline: 1.0097x; 1.0097x over previous
//
#include <hip/hip_runtime.h>
#include <hip/hip_bf16.h>
#include <stdint.h>

typedef __attribute__((ext_vector_type(8))) __bf16 bf16x8;
typedef __attribute__((ext_vector_type(4))) float f32x4;

constexpr int K_DIM = 4096;
constexpr int N_DIM = 11008;
constexpr int M_DIM = 256;   // B*S
constexpr int TM = 256;      // full M per block
constexpr int TN = 64;       // N cols per block
constexpr int BK = 64;       // K per tile
constexpr int NT = 512;      // 8 waves: 4M x 2N, each wave 64M x 32N
constexpr int KT_ALL = K_DIM / BK;   // 64
constexpr int KSPLIT = 3;    // grid = 172*3 = 516 ~ 2 blocks/CU
constexpr int WTILE = TN * BK;       // 4096 int8 = 4 KB per packed W tile

__device__ __forceinline__ void gload_lds16(const __bf16* gptr, __bf16* lptr) {
  __builtin_amdgcn_global_load_lds(
      (const __attribute__((address_space(1))) uint32_t*)gptr,
      (__attribute__((address_space(3))) uint32_t*)lptr, 16, 0, 0);
}

__device__ __forceinline__ bf16x8 cvt8f(const float4 u0, const float4 u1) {
  bf16x8 v;
  v[0] = (__bf16)u0.x; v[1] = (__bf16)u0.y; v[2] = (__bf16)u0.z; v[3] = (__bf16)u0.w;
  v[4] = (__bf16)u1.x; v[5] = (__bf16)u1.y; v[6] = (__bf16)u1.z; v[7] = (__bf16)u1.w;
  return v;
}
__device__ __forceinline__ bf16x8 cvt8i(const int4 a, const int4 b) {
  bf16x8 v;
  v[0] = (__bf16)(float)a.x; v[1] = (__bf16)(float)a.y;
  v[2] = (__bf16)(float)a.z; v[3] = (__bf16)(float)a.w;
  v[4] = (__bf16)(float)b.x; v[5] = (__bf16)(float)b.y;
  v[6] = (__bf16)(float)b.z; v[7] = (__bf16)(float)b.w;
  return v;
}

// x fp32 [256][4096] -> xws bf16 row-major (coalesced both sides). ~2 us.
__global__ void cvt_x_kernel(const float* __restrict__ x, __bf16* __restrict__ ws) {
  const int i = (blockIdx.x * 256 + threadIdx.x) * 8;
  const float4 u0 = ((const float4*)(x + i))[0];
  const float4 u1 = ((const float4*)(x + i))[1];
  *(bf16x8*)(ws + i) = cvt8f(u0, u1);
}

// w int32 [11008][4096] (int8-widened) -> wp TRUE int8, tile-major:
// wp[nb][kt] = 4 KB tile, elem (wrow, col) at wrow*64 + col
// (rows nb*64+wrow, cols kt*64+col). 180 MB -> 45 MB: the GEMM then reads
// 4x fewer W bytes, fully linear per block. Thread j: writes out bytes
// [j*32, j*32+32) (wave = 2 KB linear store stream); reads 32 consecutive
// int32 = 128 B = one full L2 line (L3-hot: harness restore just wrote w).
__global__ void pack_w_kernel(const int* __restrict__ w, int8_t* __restrict__ wp) {
  const int j = blockIdx.x * 256 + threadIdx.x;    // 1,409,024 threads
  const int e = j * 32;                            // out byte index
  const int tile = e >> 12;
  const int o = e & 4095;
  const int wrow = o >> 6;
  const int col0 = o & 63;                         // 0 or 32
  const int nb = tile >> 6, kt = tile & 63;
  const int4* src = (const int4*)(w + (int64_t)(nb * 64 + wrow) * K_DIM + kt * 64 + col0);
  int pk[8];
#pragma unroll
  for (int q = 0; q < 8; ++q) {
    const int4 a = src[q];
    pk[q] = (a.x & 0xFF) | ((a.y & 0xFF) << 8) | ((a.z & 0xFF) << 16) | (a.w << 24);
  }
  int4* dst = (int4*)(wp + (size_t)e);
  dst[0] = make_int4(pk[0], pk[1], pk[2], pk[3]);
  dst[1] = make_int4(pk[4], pk[5], pk[6], pk[7]);
}

template<bool A_WS, bool W_PK>
__global__ __launch_bounds__(NT, 4) void int8_linear_kernel(
    const float* __restrict__ x,     // [256,4096] fp32 (fallback)
    const __bf16* __restrict__ xws,  // [256,4096] bf16 (A_WS)
    const int*   __restrict__ w,     // [11008,4096] int32 (fallback)
    const int8_t* __restrict__ wp,   // packed tile-major int8 (W_PK)
    const float* __restrict__ scale, // [11008]
    const float* __restrict__ bias,  // [11008]
    float*       __restrict__ out)   // [256,11008] fp32, pre-zeroed, atomics
{
  // R5 structure; only W's global form changed: 8 B/thread/phase of packed
  // int8, read linearly, unpacked to bf16 in regs, committed to swizzled LDS
  // AFTER compute (R0-proven wload/commitW split -> load can't stall compute).
  __shared__ __bf16 As[2][TM * BK];      // 2 x 32 KB
  __shared__ __bf16 Wsh[2][TN * BK];     // 2 x 8 KB   -> 80 KB, 2 blocks/CU

  const int tid  = threadIdx.x;
  const int lane = tid & 63;
  const int wv   = tid >> 6;
  const int quad = lane >> 4;
  const int l16  = lane & 15;
  const int m_base = (wv >> 1) * 64;   // 4 M-groups
  const int wn     = wv & 1;           // 2 N-groups
  const int nb     = blockIdx.x;       // N-block 0..171
  const int n_base = nb * TN;
  const int kc     = blockIdx.y;

  // split-K tile range over 64 tiles: {21,21,22}
  const int t0 = (kc * KT_ALL) / KSPLIT;
  const int t1 = ((kc + 1) * KT_ALL) / KSPLIT;
  const int ntile = t1 - t0;

  // W LDS geometry: thread owns 8 int8 of row wrow, chunk wchunk
  const int wrow   = tid >> 3;
  const int wchunk = tid & 7;
  const int wslot  = wchunk ^ (wrow & 7);

  f32x4 acc[4][2];
#pragma unroll
  for (int i = 0; i < 4; ++i)
#pragma unroll
    for (int j = 0; j < 2; ++j) acc[i][j] = (f32x4){0.f, 0.f, 0.f, 0.f};

  uint2 pw;      // 8 packed int8 of W in flight
  int4  wi0, wi1;  // fallback path (int32 direct)
  auto wload = [&](int t) {
    if (W_PK) {
      pw = *(const uint2*)(wp + (size_t)(nb * KT_ALL + t0 + t) * WTILE + tid * 8);
    } else {
      const int4* p = (const int4*)(w + (int64_t)(n_base + wrow) * K_DIM +
                                    (t0 + t) * BK + wchunk * 8);
      wi0 = p[0]; wi1 = p[1];
    }
  };
  auto commitW = [&](__bf16* wbuf) {
    bf16x8 v;
    if (W_PK) {
#pragma unroll
      for (int e = 0; e < 4; ++e)
        v[e] = (__bf16)(float)(int)(int8_t)((pw.x >> (8 * e)) & 0xFF);
#pragma unroll
      for (int e = 0; e < 4; ++e)
        v[4 + e] = (__bf16)(float)(int)(int8_t)((pw.y >> (8 * e)) & 0xFF);
    } else {
      v = cvt8i(wi0, wi1);
    }
    *(bf16x8*)(wbuf + wrow * BK + wslot * 8) = v;
  };
  // A: 2048 16B-chunks / 512 thr = 4 gload_lds each; source-swizzled
  // (rule #21), L2-resident (xws = 2 MB).
  auto a_stage = [&](int t, __bf16* abuf) {
    const int kt = t0 + t;
    if (A_WS) {
#pragma unroll
      for (int j = 0; j < 4; ++j) {
        const int c = j * 512 + tid;
        const int row = c >> 3;
        const int k8 = (c & 7) ^ (row & 7);
        gload_lds16(xws + (int64_t)row * K_DIM + kt * BK + k8 * 8, abuf + c * 8);
      }
    } else {
#pragma unroll
      for (int j = 0; j < 4; ++j) {
        const int c = j * 512 + tid;
        const int row = c >> 3;
        const int k8 = c & 7;
        const float* s = x + (int64_t)row * K_DIM + kt * BK + k8 * 8;
        const bf16x8 vv = cvt8f(((const float4*)s)[0], ((const float4*)s)[1]);
        *(bf16x8*)(abuf + row * BK + (k8 ^ (row & 7)) * 8) = vv;
      }
    }
  };
  auto compute = [&](const __bf16* abuf, const __bf16* wbuf) {
#pragma unroll
    for (int ks = 0; ks < 2; ++ks) {
      bf16x8 a[4], b[2];
#pragma unroll
      for (int mi = 0; mi < 4; ++mi) {
        const int m = m_base + mi * 16 + l16;
        const int slot = (ks * 4 + quad) ^ (m & 7);
        a[mi] = *(const bf16x8*)(abuf + m * BK + slot * 8);
      }
#pragma unroll
      for (int ni = 0; ni < 2; ++ni) {
        const int n = wn * 32 + ni * 16 + l16;
        const int slot = (ks * 4 + quad) ^ (n & 7);
        b[ni] = *(const bf16x8*)(wbuf + n * BK + slot * 8);
      }
#pragma unroll
      for (int mi = 0; mi < 4; ++mi)
#pragma unroll
        for (int ni = 0; ni < 2; ++ni)
          acc[mi][ni] = __builtin_amdgcn_mfma_f32_16x16x32_bf16(
              a[mi], b[ni], acc[mi][ni], 0, 0, 0);
    }
  };

  // Prologue: tile 0 staged (W via regs->LDS, A via gload_lds).
  wload(0);
  commitW(Wsh[0]);
  a_stage(0, As[0]);
  __syncthreads();

  // 2-barrier double-buffered loop: loads for t+1 issue BEFORE compute(t);
  // W unpack+commit lands AFTER compute, before the barrier.
  for (int t = 0; t < ntile; ++t) {
    const int nxt = (t + 1) & 1;
    const bool more = (t + 1 < ntile);
    if (more) { wload(t + 1); a_stage(t + 1, As[nxt]); }
    compute(As[t & 1], Wsh[t & 1]);
    if (more) commitW(Wsh[nxt]);
    __syncthreads();
  }

  // Epilogue: C/D layout col=lane&15, row=quad*4+reg (m89-verified).
  // Scale per-partial (linear); bias added exactly once by the kc==0 block.
#pragma unroll
  for (int ni = 0; ni < 2; ++ni) {
    const int col = n_base + wn * 32 + ni * 16 + l16;
    const float sc = scale[col];
    const float bi = (kc == 0) ? bias[col] : 0.0f;
#pragma unroll
    for (int mi = 0; mi < 4; ++mi) {
      const int row0 = m_base + mi * 16 + quad * 4;
#pragma unroll
      for (int r = 0; r < 4; ++r)
        unsafeAtomicAdd(out + (int64_t)(row0 + r) * N_DIM + col,
                        acc[mi][ni][r] * sc + bi);
    }
  }
}

extern "C" void kernel_launch(void* const* d_in, const int* in_sizes, int n_in,
                              void* d_out, int out_size, void* d_ws, size_t ws_size,
                              hipStream_t stream) {
  const float* x     = (const float*)d_in[0];
  const int*   w     = (const int*)d_in[1];
  const float* scale = (const float*)d_in[2];
  const float* bias  = (const float*)d_in[3];
  float* out = (float*)d_out;

  const size_t xws_bytes = (size_t)M_DIM * K_DIM * sizeof(__bf16);   // 2 MB
  const size_t wp_bytes  = (size_t)N_DIM * K_DIM;                    // 45 MB
  __bf16* xws = (__bf16*)d_ws;
  int8_t* wpp = (int8_t*)((char*)d_ws + xws_bytes);

  // split-K partials accumulate via atomics -> zero the output first
  hipMemsetAsync(out, 0, (size_t)M_DIM * N_DIM * sizeof(float), stream);

  dim3 grid(N_DIM / TN, KSPLIT), block(NT);
  if (ws_size >= xws_bytes + wp_bytes) {
    cvt_x_kernel<<<M_DIM * K_DIM / 2048, 256, 0, stream>>>(x, xws);
    pack_w_kernel<<<(int)(((size_t)N_DIM * K_DIM / 32) / 256), 256, 0, stream>>>(w, wpp);
    int8_linear_kernel<true, true><<<grid, block, 0, stream>>>(
        x, xws, w, wpp, scale, bias, out);
  } else if (ws_size >= xws_bytes) {
    cvt_x_kernel<<<M_DIM * K_DIM / 2048, 256, 0, stream>>>(x, xws);
    int8_linear_kernel<true, false><<<grid, block, 0, stream>>>(
        x, xws, w, wpp, scale, bias, out);
  } else {
    int8_linear_kernel<false, false><<<grid, block, 0, stream>>>(
        x, xws, w, wpp, scale, bias, out);
  }
}